// Round 6
// baseline (115.947 us; speedup 1.0000x reference)
//
#include <hip/hip_runtime.h>
#include <math.h>

#define NB 4096     // batch
#define ND 512      // dim

typedef __bf16 bf16x8 __attribute__((ext_vector_type(8)));
typedef unsigned short u16x8 __attribute__((ext_vector_type(8)));
typedef _Float16 f16x8 __attribute__((ext_vector_type(8)));
typedef _Float16 f16x4 __attribute__((ext_vector_type(4)));
typedef float f32x4 __attribute__((ext_vector_type(4)));

__device__ inline unsigned short f2bf(float f){
  unsigned u = __float_as_uint(f);
  u += 0x7FFFu + ((u >> 16) & 1u);      // round-to-nearest-even
  return (unsigned short)(u >> 16);
}

// async global->LDS, 16B per lane. LDS dest = wave-uniform base + lane*16
// (global side is per-lane free -> we permute it for the XOR bank swizzle).
__device__ inline void gl2lds16(const unsigned short* g, unsigned short* l){
  __builtin_amdgcn_global_load_lds(
      (const __attribute__((address_space(1))) unsigned int*)g,
      (__attribute__((address_space(3))) unsigned int*)l, 16, 0, 0);
}

// fused: feats fp32 -> bf16; block 0 also packs labels->u8 (C=256 fits a byte)
__global__ __launch_bounds__(256) void convert_init(const float* feats, unsigned short* fb,
                                                    const int* labels, unsigned char* lab8){
  size_t idx = (size_t)blockIdx.x * 256 + threadIdx.x;  // group of 8 elements
  const float4* p = (const float4*)(feats + idx * 8);
  float4 x0 = p[0], x1 = p[1];
  u16x8 v;
  v[0]=f2bf(x0.x); v[1]=f2bf(x0.y); v[2]=f2bf(x0.z); v[3]=f2bf(x0.w);
  v[4]=f2bf(x1.x); v[5]=f2bf(x1.y); v[6]=f2bf(x1.z); v[7]=f2bf(x1.w);
  *(u16x8*)(fb + idx * 8) = v;

  if (blockIdx.x == 0){
    const int t = threadIdx.x;
    const int4* lp = (const int4*)(labels + t*16);
    int4 a = lp[0], b = lp[1], c = lp[2], d = lp[3];
    unsigned char pk[16] = {
      (unsigned char)a.x,(unsigned char)a.y,(unsigned char)a.z,(unsigned char)a.w,
      (unsigned char)b.x,(unsigned char)b.y,(unsigned char)b.z,(unsigned char)b.w,
      (unsigned char)c.x,(unsigned char)c.y,(unsigned char)c.z,(unsigned char)c.w,
      (unsigned char)d.x,(unsigned char)d.y,(unsigned char)d.z,(unsigned char)d.w };
    *(int4*)(lab8 + t*16) = *(const int4*)pk;
  }
}

// PASS 1: sim = F F^T, 128x128 tile, 4 waves (64x64 each), 16x16x32 bf16 MFMA.
// Restructured K-loop (no per-iter barriers):
//   - A half-K tile (128x256 bf16 = 64 KB) resident in LDS, staged per phase
//     via global_load_lds with XOR chunk swizzle (bank-conflict-free b128 reads)
//   - B fragments loaded per-lane from global (fb is L2-resident) in exact
//     MFMA B-layout -> no LDS, no barrier dependency, deep pipelining
// Grid: 528 linear blocks = upper triangle; off-diag blocks store the tile AND
// its transpose (dot products are bitwise-commutative).
__global__ __launch_bounds__(256) void gemm_sim(const unsigned short* fb, _Float16* sim){
  __shared__ unsigned short As[128*256];   // 64 KB, rows of 256 shorts (16 chunks of 16B x2)

  // triangular decode: t -> (by, bx), bx >= by, 32 blocks/dim
  const int t  = blockIdx.x;
  const int by = (int)((65.0 - sqrt(4225.0 - 8.0*(double)t)) * 0.5);
  const int bx = by + t - (by*(65 - by))/2;

  const int tid  = threadIdx.x;
  const int lane = tid & 63;
  const int wave = tid >> 6;
  const int m0   = (wave >> 1) * 64;
  const int n0   = (wave & 1) * 64;
  const int quad = lane >> 4;
  const int l15  = lane & 15;
  const int p3   = l15 & 7;          // low 3 bits of the row a lane reads -> swizzle key

  // staging geometry: one gl2lds16 = 1 KB = 2 rows (row stride 512 B)
  const int rsub = lane >> 5;        // which of the 2 rows
  const int cch  = lane & 31;        // 16B chunk within row

  // B fragment global bases: lane (quad,l15) reads B[k=quad*8+j][n=n0+sn*16+l15]
  // = fb[n*ND + k], one 16B load; per-iter offset is an immediate.
  const unsigned short* bb[4];
#pragma unroll
  for (int sn=0;sn<4;++sn)
    bb[sn] = fb + (size_t)(bx*128 + n0 + sn*16 + l15) * ND + quad*8;

  f32x4 acc[4][4];
#pragma unroll
  for (int i=0;i<4;++i)
#pragma unroll
    for (int j=0;j<4;++j) acc[i][j] = (f32x4){0.f,0.f,0.f,0.f};

  for (int ph = 0; ph < 2; ++ph){
    __syncthreads();   // prior phase's LDS reads complete before overwrite
    // stage A half-K: LDS[row][c] = G[row][(c&24)|((c^row)&7)]  (XOR swizzle)
#pragma unroll
    for (int i = 0; i < 16; ++i){
      const int row = wave*32 + i*2 + rsub;
      const int gc  = (cch & 24) | ((cch ^ row) & 7);
      gl2lds16(fb + (size_t)(by*128 + row) * ND + ph*256 + gc*8,
               &As[(wave*32 + i*2)*256]);
    }
    __syncthreads();   // vmcnt drained by compiler before barrier

    // barrier-free K-loop: 8 iters x K=32
#pragma unroll 2
    for (int i = 0; i < 8; ++i){
      const int chsw = (((i*4 + quad) ^ p3) * 8);   // swizzled chunk -> short offset
      bf16x8 af[4], bfr[4];
#pragma unroll
      for (int s=0;s<4;++s)
        af[s] = __builtin_bit_cast(bf16x8, *(const u16x8*)&As[(m0 + s*16 + l15)*256 + chsw]);
#pragma unroll
      for (int sn=0;sn<4;++sn)
        bfr[sn] = __builtin_bit_cast(bf16x8, *(const u16x8*)(bb[sn] + ph*256 + i*32));
#pragma unroll
      for (int sm=0;sm<4;++sm)
#pragma unroll
        for (int sn=0;sn<4;++sn)
          acc[sm][sn] = __builtin_amdgcn_mfma_f32_16x16x32_bf16(af[sm], bfr[sn], acc[sm][sn], 0, 0, 0);
    }
  }

  // store epilogue. C/D layout: col = lane&15, row = quad*4 + reg per 16x16 subtile.
#pragma unroll
  for (int sm=0;sm<4;++sm){
    const int R0 = by*128 + m0 + sm*16 + quad*4;   // 4 consecutive rows
#pragma unroll
    for (int sn=0;sn<4;++sn){
      const int C = bx*128 + n0 + sn*16 + l15;
      f16x4 h;
#pragma unroll
      for (int reg=0;reg<4;++reg) h[reg] = (_Float16)acc[sm][sn][reg];
#pragma unroll
      for (int reg=0;reg<4;++reg)
        sim[(size_t)(R0+reg)*NB + C] = h[reg];           // L2 merges to full lines
      if (bx != by)
        *(f16x4*)(sim + (size_t)C*NB + R0) = h;          // transpose mirror, 8B
    }
  }
}

// PASS 2: one row per WAVE, no atomics. Wave loads its whole row (64 fp16/lane,
// 8 independent 16B loads), phase A reduce (butterfly leaves totals in every
// lane -> wave-uniform thresholds for free), phase B over the same registers,
// LDS-reduce the 4 wave losses, ONE plain store per block.
__global__ __launch_bounds__(256) void row_stats(const _Float16* sim, const unsigned char* lab8,
                                                 float* blockLoss){
  __shared__ unsigned char slab[NB];   // 4 KB: all labels as bytes
  __shared__ float wloss[4];
  const int tid  = threadIdx.x;
  *(int4*)&slab[tid*16] = *(const int4*)&lab8[tid*16];
  __syncthreads();

  const int lane = tid & 63;
  const int wv   = tid >> 6;
  const int r    = blockIdx.x * 4 + wv;
  const int labR = (int)slab[r];                    // wave-uniform
  const _Float16* rowp = sim + (size_t)r * NB;

  // load whole row: chunk c covers cols c*512 + lane*8 .. +7
  f16x8 h[8];
  unsigned long long lb[8];
#pragma unroll
  for (int c=0;c<8;++c)
    h[c] = *(const f16x8*)(rowp + c*512 + lane*8);
#pragma unroll
  for (int c=0;c<8;++c)
    lb[c] = *(const unsigned long long*)&slab[c*512 + lane*8];

  // phase A: sum, min_pos (same & <1-eps), max_neg (diff)
  float s = 0.f, mp = 3.0e38f, mn = -3.0e38f;
#pragma unroll
  for (int c=0;c<8;++c){
    const unsigned long long L = lb[c];
#pragma unroll
    for (int j=0;j<8;++j){
      const float x = (float)h[c][j];
      const int lj = (int)((L >> (8*j)) & 0xffULL);
      s += x;
      if (lj == labR){ if (x < 0.99999f) mp = fminf(mp, x); }
      else           { mn = fmaxf(mn, x); }
    }
  }
#pragma unroll
  for (int o=1;o<64;o<<=1){
    s  += __shfl_xor(s, o, 64);
    mp  = fminf(mp, __shfl_xor(mp, o, 64));
    mn  = fmaxf(mn, __shfl_xor(mn, o, 64));
  }
  const bool hp = (mp < 1.0e38f), hn = (mn > -1.0e38f);
  const float mpr = hp ? mp : 1.0e9f;               // BIG like reference
  const float mnr = hn ? mn : -1.0e9f;
  const float mean_ = (s * (1.0f/(float)NB) + 0.5f*(mpr+mnr)) * 0.5f;
  const float tpp = mnr + 0.1f;                     // pp: x < max_neg + MARGIN
  const float tnm = mpr - 0.1f;                     // nm: x > min_pos - MARGIN

  // phase B: sigma, fp, fn from the same registers
  float sg = 0.f, fps = 0.f, fns = 0.f;
#pragma unroll
  for (int c=0;c<8;++c){
    const unsigned long long L = lb[c];
#pragma unroll
    for (int j=0;j<8;++j){
      const float x = (float)h[c][j];
      const int lj = (int)((L >> (8*j)) & 0xffULL);
      if (lj != labR){
        const float d = x - mean_; sg += d*d;
        if (x > tnm) fns += __expf((x - 0.5f) * 40.0f);
      } else if (x < 0.99999f && x < tpp){
        fps += __expf(-(x - 0.5f) * 2.0f);
      }
    }
  }
#pragma unroll
  for (int o=1;o<64;o<<=1){
    sg  += __shfl_xor(sg,  o, 64);
    fps += __shfl_xor(fps, o, 64);
    fns += __shfl_xor(fns, o, 64);
  }

  if (lane == 0){
    wloss[wv] = (hp && hn && fps > 0.f && fns > 0.f)
                ? (logf(1.f + fps) + logf(1.f + fns) + 0.1f * sg) : 0.f;
  }
  __syncthreads();
  if (tid == 0)
    blockLoss[blockIdx.x] = wloss[0] + wloss[1] + wloss[2] + wloss[3];
}

__global__ __launch_bounds__(1024) void finalize(const float* blockLoss, float* out){
  const int tid = threadIdx.x;
  float l = blockLoss[tid];          // exactly NB/4 == 1024 entries
#pragma unroll
  for (int o=1;o<64;o<<=1) l += __shfl_xor(l, o, 64);
  __shared__ float red[16];
  if ((tid & 63) == 0) red[tid >> 6] = l;
  __syncthreads();
  if (tid == 0){
    float t = 0.f;
#pragma unroll
    for (int i=0;i<16;++i) t += red[i];
    out[0] = t * (1.0f/(float)NB);
  }
}

extern "C" void kernel_launch(void* const* d_in, const int* in_sizes, int n_in,
                              void* d_out, int out_size, void* d_ws, size_t ws_size,
                              hipStream_t stream) {
  (void)in_sizes; (void)n_in; (void)out_size; (void)ws_size;
  const float* feats  = (const float*)d_in[0];
  const int*   labels = (const int*)d_in[1];
  float* out = (float*)d_out;

  // ws layout: sim fp16 (32MB) | fb bf16 (4MB) | lab8 (4KB) | blockLoss (4KB)
  _Float16* sim       = (_Float16*)d_ws;
  unsigned short* fb  = (unsigned short*)(sim + (size_t)NB*NB);
  unsigned char* lab8 = (unsigned char*)(fb + (size_t)NB*ND);
  float* blockLoss    = (float*)(lab8 + NB);

  convert_init<<<dim3((NB*ND/8)/256), dim3(256), 0, stream>>>(feats, fb, labels, lab8);

  gemm_sim<<<dim3(528), dim3(256), 0, stream>>>(fb, sim);

  row_stats<<<dim3(NB/4), dim3(256), 0, stream>>>(sim, lab8, blockLoss);

  finalize<<<dim3(1), dim3(1024), 0, stream>>>(blockLoss, out);
}

// Round 7
// 106.411 us; speedup vs baseline: 1.0896x; 1.0896x over previous
//
#include <hip/hip_runtime.h>
#include <math.h>

#define NB 4096     // batch
#define ND 512      // dim

typedef __bf16 bf16x8 __attribute__((ext_vector_type(8)));
typedef unsigned short u16x8 __attribute__((ext_vector_type(8)));
typedef _Float16 f16x8 __attribute__((ext_vector_type(8)));
typedef _Float16 f16x4 __attribute__((ext_vector_type(4)));
typedef float f32x4 __attribute__((ext_vector_type(4)));

__device__ inline unsigned short f2bf(float f){
  unsigned u = __float_as_uint(f);
  u += 0x7FFFu + ((u >> 16) & 1u);      // round-to-nearest-even
  return (unsigned short)(u >> 16);
}

// async global->LDS, 16B per lane. LDS dest = wave-uniform base + lane*16.
__device__ inline void gl2lds16(const unsigned short* g, unsigned short* l){
  __builtin_amdgcn_global_load_lds(
      (const __attribute__((address_space(1))) unsigned int*)g,
      (__attribute__((address_space(3))) unsigned int*)l, 16, 0, 0);
}

// fused: feats fp32 -> bf16; block 0 also packs labels->u8 (C=256 fits a byte)
__global__ __launch_bounds__(256) void convert_init(const float* feats, unsigned short* fb,
                                                    const int* labels, unsigned char* lab8){
  size_t idx = (size_t)blockIdx.x * 256 + threadIdx.x;  // group of 8 elements
  const float4* p = (const float4*)(feats + idx * 8);
  float4 x0 = p[0], x1 = p[1];
  u16x8 v;
  v[0]=f2bf(x0.x); v[1]=f2bf(x0.y); v[2]=f2bf(x0.z); v[3]=f2bf(x0.w);
  v[4]=f2bf(x1.x); v[5]=f2bf(x1.y); v[6]=f2bf(x1.z); v[7]=f2bf(x1.w);
  *(u16x8*)(fb + idx * 8) = v;

  if (blockIdx.x == 0){
    const int t = threadIdx.x;
    const int4* lp = (const int4*)(labels + t*16);
    int4 a = lp[0], b = lp[1], c = lp[2], d = lp[3];
    unsigned char pk[16] = {
      (unsigned char)a.x,(unsigned char)a.y,(unsigned char)a.z,(unsigned char)a.w,
      (unsigned char)b.x,(unsigned char)b.y,(unsigned char)b.z,(unsigned char)b.w,
      (unsigned char)c.x,(unsigned char)c.y,(unsigned char)c.z,(unsigned char)c.w,
      (unsigned char)d.x,(unsigned char)d.y,(unsigned char)d.z,(unsigned char)d.w };
    *(int4*)(lab8 + t*16) = *(const int4*)pk;
  }
}

// PASS 1: sim = F F^T (bf16 in, fp32 acc, fp16 out). 128x64 tiles, 4 waves
// (each 32 rows x 64 cols, 2x4 16x16x32-MFMA frags, acc=32 VGPR), BK=32,
// m97-style global_load_lds width-16 staging (R5-proven inner loop).
// Grid: 1056 staircase blocks (bx2 in [2*by, 64)) -> 4.1 blocks/CU, double
// R5's resident waves (fixes the grid-limited 18% occupancy). Each block
// stores its tile AND its transpose; overlap double-writes carry bitwise-
// identical values (MFMA dot products are A/B-commutative bitwise).
__global__ __launch_bounds__(256) void gemm_sim(const unsigned short* fb, _Float16* sim){
  __shared__ unsigned short As[128*32];   // 8 KB
  __shared__ unsigned short Bs[64*32];    // 4 KB

  // staircase decode: t -> (by, bx2): S(by)=by*(65-by); exact at boundaries
  const int t   = blockIdx.x;
  const int by  = (int)((65.0 - sqrt(4225.0 - 4.0*(double)t)) * 0.5);
  const int bx2 = 2*by + (t - by*(65 - by));

  const int tid  = threadIdx.x;
  const int lane = tid & 63;
  const int wave = tid >> 6;
  const int m0   = wave * 32;        // wave's 32-row strip of the 128-row tile
  const int quad = lane >> 4;
  const int l15  = lane & 15;

  // staging geometry: lane l -> row l/4, col (l%4)*8; one call = 16 rows x 64B
  const int srow = lane >> 2;
  const int scol = (lane & 3) * 8;
  const unsigned short* aseg = fb + (size_t)(by*128 + wave*32 + srow) * ND + scol;
  const unsigned short* bseg = fb + (size_t)(bx2*64 + wave*16 + srow) * ND + scol;
  unsigned short* abase = &As[(wave*32) * 32];
  unsigned short* bbase = &Bs[(wave*16) * 32];

  f32x4 acc[2][4];
#pragma unroll
  for (int i=0;i<2;++i)
#pragma unroll
    for (int j=0;j<4;++j) acc[i][j] = (f32x4){0.f,0.f,0.f,0.f};

  for (int k0 = 0; k0 < ND; k0 += 32){
    __syncthreads();   // previous iter's LDS reads complete
    gl2lds16(aseg + k0,         abase);            // A rows [w*32, +16)
    gl2lds16(aseg + k0 + 16*ND, abase + 16*32);    // A rows [w*32+16, +16)
    gl2lds16(bseg + k0,         bbase);            // B rows [w*16, +16)
    __syncthreads();   // compiler drains vmcnt before barrier

    bf16x8 af[2], bfr[4];
#pragma unroll
    for (int s = 0; s < 2; ++s)
      af[s]  = __builtin_bit_cast(bf16x8, *(const u16x8*)&As[(m0 + s*16 + l15)*32 + quad*8]);
#pragma unroll
    for (int sn = 0; sn < 4; ++sn)
      bfr[sn] = __builtin_bit_cast(bf16x8, *(const u16x8*)&Bs[(sn*16 + l15)*32 + quad*8]);
#pragma unroll
    for (int sm=0;sm<2;++sm)
#pragma unroll
      for (int sn=0;sn<4;++sn)
        acc[sm][sn] = __builtin_amdgcn_mfma_f32_16x16x32_bf16(af[sm], bfr[sn], acc[sm][sn], 0, 0, 0);
  }

  // store epilogue. C/D layout: col = lane&15, row = quad*4 + reg per 16x16 subtile.
#pragma unroll
  for (int sm=0;sm<2;++sm){
    const int R0 = by*128 + m0 + sm*16 + quad*4;   // 4 consecutive rows
#pragma unroll
    for (int sn=0;sn<4;++sn){
      const int C = bx2*64 + sn*16 + l15;
      f16x4 h;
#pragma unroll
      for (int reg=0;reg<4;++reg) h[reg] = (_Float16)acc[sm][sn][reg];
#pragma unroll
      for (int reg=0;reg<4;++reg)
        sim[(size_t)(R0+reg)*NB + C] = h[reg];     // L2 merges to full lines
      *(f16x4*)(sim + (size_t)C*NB + R0) = h;      // transpose mirror, 8B
    }
  }
}

// PASS 2: one row per WAVE, no atomics. Wave loads its whole row (64 fp16/lane,
// 8 independent 16B loads), phase A reduce (butterfly leaves totals in every
// lane -> wave-uniform thresholds for free), phase B over the same registers,
// LDS-reduce the 4 wave losses, ONE plain store per block.
__global__ __launch_bounds__(256) void row_stats(const _Float16* sim, const unsigned char* lab8,
                                                 float* blockLoss){
  __shared__ unsigned char slab[NB];   // 4 KB: all labels as bytes
  __shared__ float wloss[4];
  const int tid  = threadIdx.x;
  *(int4*)&slab[tid*16] = *(const int4*)&lab8[tid*16];
  __syncthreads();

  const int lane = tid & 63;
  const int wv   = tid >> 6;
  const int r    = blockIdx.x * 4 + wv;
  const int labR = (int)slab[r];                    // wave-uniform
  const _Float16* rowp = sim + (size_t)r * NB;

  // load whole row: chunk c covers cols c*512 + lane*8 .. +7
  f16x8 h[8];
  unsigned long long lb[8];
#pragma unroll
  for (int c=0;c<8;++c)
    h[c] = *(const f16x8*)(rowp + c*512 + lane*8);
#pragma unroll
  for (int c=0;c<8;++c)
    lb[c] = *(const unsigned long long*)&slab[c*512 + lane*8];

  // phase A: sum, min_pos (same & <1-eps), max_neg (diff)
  float s = 0.f, mp = 3.0e38f, mn = -3.0e38f;
#pragma unroll
  for (int c=0;c<8;++c){
    const unsigned long long L = lb[c];
#pragma unroll
    for (int j=0;j<8;++j){
      const float x = (float)h[c][j];
      const int lj = (int)((L >> (8*j)) & 0xffULL);
      s += x;
      if (lj == labR){ if (x < 0.99999f) mp = fminf(mp, x); }
      else           { mn = fmaxf(mn, x); }
    }
  }
#pragma unroll
  for (int o=1;o<64;o<<=1){
    s  += __shfl_xor(s, o, 64);
    mp  = fminf(mp, __shfl_xor(mp, o, 64));
    mn  = fmaxf(mn, __shfl_xor(mn, o, 64));
  }
  const bool hp = (mp < 1.0e38f), hn = (mn > -1.0e38f);
  const float mpr = hp ? mp : 1.0e9f;               // BIG like reference
  const float mnr = hn ? mn : -1.0e9f;
  const float mean_ = (s * (1.0f/(float)NB) + 0.5f*(mpr+mnr)) * 0.5f;
  const float tpp = mnr + 0.1f;                     // pp: x < max_neg + MARGIN
  const float tnm = mpr - 0.1f;                     // nm: x > min_pos - MARGIN

  // phase B: sigma, fp, fn from the same registers
  float sg = 0.f, fps = 0.f, fns = 0.f;
#pragma unroll
  for (int c=0;c<8;++c){
    const unsigned long long L = lb[c];
#pragma unroll
    for (int j=0;j<8;++j){
      const float x = (float)h[c][j];
      const int lj = (int)((L >> (8*j)) & 0xffULL);
      if (lj != labR){
        const float d = x - mean_; sg += d*d;
        if (x > tnm) fns += __expf((x - 0.5f) * 40.0f);
      } else if (x < 0.99999f && x < tpp){
        fps += __expf(-(x - 0.5f) * 2.0f);
      }
    }
  }
#pragma unroll
  for (int o=1;o<64;o<<=1){
    sg  += __shfl_xor(sg,  o, 64);
    fps += __shfl_xor(fps, o, 64);
    fns += __shfl_xor(fns, o, 64);
  }

  if (lane == 0){
    wloss[wv] = (hp && hn && fps > 0.f && fns > 0.f)
                ? (logf(1.f + fps) + logf(1.f + fns) + 0.1f * sg) : 0.f;
  }
  __syncthreads();
  if (tid == 0)
    blockLoss[blockIdx.x] = wloss[0] + wloss[1] + wloss[2] + wloss[3];
}

__global__ __launch_bounds__(1024) void finalize(const float* blockLoss, float* out){
  const int tid = threadIdx.x;
  float l = blockLoss[tid];          // exactly NB/4 == 1024 entries
#pragma unroll
  for (int o=1;o<64;o<<=1) l += __shfl_xor(l, o, 64);
  __shared__ float red[16];
  if ((tid & 63) == 0) red[tid >> 6] = l;
  __syncthreads();
  if (tid == 0){
    float t = 0.f;
#pragma unroll
    for (int i=0;i<16;++i) t += red[i];
    out[0] = t * (1.0f/(float)NB);
  }
}

extern "C" void kernel_launch(void* const* d_in, const int* in_sizes, int n_in,
                              void* d_out, int out_size, void* d_ws, size_t ws_size,
                              hipStream_t stream) {
  (void)in_sizes; (void)n_in; (void)out_size; (void)ws_size;
  const float* feats  = (const float*)d_in[0];
  const int*   labels = (const int*)d_in[1];
  float* out = (float*)d_out;

  // ws layout: sim fp16 (32MB) | fb bf16 (4MB) | lab8 (4KB) | blockLoss (4KB)
  _Float16* sim       = (_Float16*)d_ws;
  unsigned short* fb  = (unsigned short*)(sim + (size_t)NB*NB);
  unsigned char* lab8 = (unsigned char*)(fb + (size_t)NB*ND);
  float* blockLoss    = (float*)(lab8 + NB);

  convert_init<<<dim3((NB*ND/8)/256), dim3(256), 0, stream>>>(feats, fb, labels, lab8);

  gemm_sim<<<dim3(1056), dim3(256), 0, stream>>>(fb, sim);

  row_stats<<<dim3(NB/4), dim3(256), 0, stream>>>(sim, lab8, blockLoss);

  finalize<<<dim3(1), dim3(1024), 0, stream>>>(blockLoss, out);
}